// Round 4
// baseline (707.826 us; speedup 1.0000x reference)
//
#include <hip/hip_runtime.h>
#include <math.h>

#define SQ 2048      // seq len
#define DE 512       // d_embedding
#define DH 64        // d_head
#define CW 128       // half-window
#define W2 256       // window width
#define NH 8         // heads
#define NQ 4         // queries per block
#define UW (W2 + NQ - 1)  // union window width = 259
#define NT 512       // threads per block
#define NW 8         // waves per block

// ---------------- prep: copy x -> cur, transpose Wq/Wk/Wvd to [h][e][c] ----------------
__global__ __launch_bounds__(256) void prep_kernel(
    const float* __restrict__ x, const float* __restrict__ Wq,
    const float* __restrict__ Wk, const float* __restrict__ Wvd,
    float* __restrict__ cur, float* __restrict__ WTq,
    float* __restrict__ WTk, float* __restrict__ WTv) {
  int i = blockIdx.x * 256 + threadIdx.x;
  if (i < SQ * DE) cur[i] = x[i];
  if (i < NH * DE * DH) {
    int c = i & 63;           // dh index
    int e = (i >> 6) & 511;   // embedding index
    int h = i >> 15;
    int src = (h * DH + c) * DE + e;
    WTq[i] = Wq[src];
    WTk[i] = Wk[src];
    WTv[i] = Wvd[src];
  }
}

// ---------------- qkv0: q/k/v for head 0 straight from x ----------------
// NOTE: no min-waves in __launch_bounds__ — forcing 4 waves/EU squeezed VGPR to 64
// and spilled ~80 dwords/thread to scratch (WRITE_SIZE 83 MB vs 5.6 MB true stores).
__global__ __launch_bounds__(NT) void qkv0_kernel(
    const float* __restrict__ x,
    const float* __restrict__ WTq, const float* __restrict__ WTk,
    const float* __restrict__ WTv,
    float* __restrict__ q, float* __restrict__ k, float* __restrict__ v) {
  __shared__ float xL[NQ][DE];            // 8 KB
  __shared__ float qP[NW][3][NQ][DH];     // 24 KB
  int tid = threadIdx.x, lane = tid & 63, wv = tid >> 6;
  int j0 = blockIdx.x * NQ;

  ((float4*)xL)[tid] = ((const float4*)(x + (size_t)j0 * DE))[tid];
  __syncthreads();

  float aq[NQ] = {0, 0, 0, 0}, ak[NQ] = {0, 0, 0, 0}, av[NQ] = {0, 0, 0, 0};
  int e0 = wv * 64;
  for (int e = e0; e < e0 + 64; e++) {
    float wq = WTq[e * DH + lane];
    float wk = WTk[e * DH + lane];
    float wvv = WTv[e * DH + lane];
#pragma unroll
    for (int r = 0; r < NQ; r++) {
      float xr = xL[r][e];
      aq[r] += xr * wq; ak[r] += xr * wk; av[r] += xr * wvv;
    }
  }
#pragma unroll
  for (int r = 0; r < NQ; r++) {
    qP[wv][0][r][lane] = aq[r];
    qP[wv][1][r][lane] = ak[r];
    qP[wv][2][r][lane] = av[r];
  }
  __syncthreads();
  for (int i = tid; i < 3 * NQ * DH; i += NT) {
    int o = i >> 8;              // 0..2 (NQ*DH = 256)
    int rem = i & 255;
    int r = rem >> 6, c = rem & 63;
    float s = 0;
#pragma unroll
    for (int w = 0; w < NW; w++) s += qP[w][o][r][c];
    float* dp = (o == 0 ? q : (o == 1 ? k : v));
    dp[(size_t)(j0 + r) * DH + c] = s;
  }
}

// ---------------- fused: attn(head h) [+ qkv(head h+1)] ----------------
// flags bit0: last head -> write out = cur/8 ; bit1: compute next-head qkv
__global__ __launch_bounds__(NT) void fused_kernel(
    float* __restrict__ cur,
    const float* __restrict__ q, const float* __restrict__ k,
    const float* __restrict__ v, const float* __restrict__ Wvu,
    const float* __restrict__ WTqn, const float* __restrict__ WTkn,
    const float* __restrict__ WTvn,
    float* __restrict__ qn, float* __restrict__ kn, float* __restrict__ vn,
    float* __restrict__ out, int flags) {
  __shared__ float qL[NQ][DH];            // 1 KB
  __shared__ float sL[NQ][W2];            // 4 KB
  __shared__ float pL[NW][NQ][DH];        // 8 KB
  __shared__ float dL[NQ][DH];            // 1 KB
  __shared__ float yL[NQ][DE];            // 8 KB (y, then new-cur)
  __shared__ float qP[NW][3][NQ][DH];     // 24 KB

  int tid = threadIdx.x, lane = tid & 63, wv = tid >> 6;
  int j0 = blockIdx.x * NQ;

  // load q rows (NQ*DH = 256 floats)
  if (tid < NQ * DH) ((float*)qL)[tid] = q[(size_t)j0 * DH + tid];
  __syncthreads();

  // ---- scores over union window: thread tid owns union offset tid ----
  if (tid < UW) {
    int goff = tid;
    int g = j0 - CW + goff;
    bool valid = (g >= 0 && g < SQ);
    int gc = valid ? g : 0;
    float acc[NQ] = {0, 0, 0, 0};
    const float4* krow = (const float4*)(k + (size_t)gc * DH);
#pragma unroll
    for (int ch = 0; ch < 16; ch++) {
      float4 kf = krow[ch];
#pragma unroll
      for (int r = 0; r < NQ; r++) {
        float4 qf = ((const float4*)qL[r])[ch];
        acc[r] += qf.x * kf.x + qf.y * kf.y + qf.z * kf.z + qf.w * kf.w;
      }
    }
#pragma unroll
    for (int r = 0; r < NQ; r++) {
      int p = goff - r;
      if (p >= 0 && p < W2) sL[r][p] = valid ? acc[r] * 0.125f : -INFINITY;
    }
  }
  __syncthreads();

  // ---- softmax: wave wv owns row wv (waves 4-7 idle; tiny phase) ----
  if (wv < NQ) {
    int r = wv;
    float m = -INFINITY;
#pragma unroll
    for (int t = 0; t < 4; t++) m = fmaxf(m, sL[r][lane + 64 * t]);
#pragma unroll
    for (int off = 32; off; off >>= 1) m = fmaxf(m, __shfl_xor(m, off));
    float ex[4], ss = 0;
#pragma unroll
    for (int t = 0; t < 4; t++) {
      ex[t] = __expf(sL[r][lane + 64 * t] - m);
      ss += ex[t];
    }
#pragma unroll
    for (int off = 32; off; off >>= 1) ss += __shfl_xor(ss, off);
    float inv = 1.0f / ss;
#pragma unroll
    for (int t = 0; t < 4; t++) sL[r][lane + 64 * t] = ex[t] * inv;
  }
  __syncthreads();

  // ---- delta = w . v_window ; 8 waves split union range; v loads coalesced ----
  {
    float dacc[NQ] = {0, 0, 0, 0};
    int gbeg = 33 * wv, gend = gbeg + 33;
    if (gend > UW) gend = UW;
    for (int goff = gbeg; goff < gend; goff++) {
      int g = j0 - CW + goff;
      int gc = g < 0 ? 0 : (g >= SQ ? SQ - 1 : g);
      float vv = v[(size_t)gc * DH + lane];
#pragma unroll
      for (int r = 0; r < NQ; r++) {
        int p = goff - r;
        if (p >= 0 && p < W2) dacc[r] += sL[r][p] * vv;
      }
    }
#pragma unroll
    for (int r = 0; r < NQ; r++) pL[wv][r][lane] = dacc[r];
  }
  __syncthreads();
  if (tid < NQ * DH) {
    int r = tid >> 6, c = tid & 63;
    float s = 0;
#pragma unroll
    for (int w = 0; w < NW; w++) s += pL[w][r][c];
    dL[r][c] = s;
  }
  __syncthreads();

  // ---- upproj + residual into yL: thread tid owns column e = tid ----
  {
    int e = tid;
    float acc[NQ] = {0, 0, 0, 0};
    const float4* wrow = (const float4*)(Wvu + (size_t)e * DH);
#pragma unroll
    for (int ch = 0; ch < 16; ch++) {
      float4 wf = wrow[ch];
#pragma unroll
      for (int r = 0; r < NQ; r++) {
        float4 df = ((const float4*)dL[r])[ch];
        acc[r] += df.x * wf.x + df.y * wf.y + df.z * wf.z + df.w * wf.w;
      }
    }
#pragma unroll
    for (int r = 0; r < NQ; r++)
      yL[r][e] = cur[(size_t)(j0 + r) * DE + e] + acc[r];
  }
  __syncthreads();

  // ---- renorm + residual update; wave wv owns row wv (waves 4-7 idle) ----
  if (wv < NQ) {
    int r = wv;
    size_t jrow = (size_t)(j0 + r) * DE;
    float s = 0;
#pragma unroll
    for (int t = 0; t < 8; t++) s += yL[r][lane + 64 * t];
#pragma unroll
    for (int off = 32; off; off >>= 1) s += __shfl_xor(s, off);
    float inv_m1 = 512.0f / s;  // 1/m1
    float y2[8], s2 = 0, s2q = 0;
#pragma unroll
    for (int t = 0; t < 8; t++) {
      y2[t] = yL[r][lane + 64 * t] * inv_m1;
      s2 += y2[t];
      s2q += y2[t] * y2[t];
    }
#pragma unroll
    for (int off = 32; off; off >>= 1) {
      s2 += __shfl_xor(s2, off);
      s2q += __shfl_xor(s2q, off);
    }
    float m2 = s2 * (1.0f / 512.0f);
    float var = (s2q - 512.0f * m2 * m2) * (1.0f / 511.0f);
    float isd = 1.0f / sqrtf(var);
#pragma unroll
    for (int t = 0; t < 8; t++) {
      int e = lane + 64 * t;
      float o = (y2[t] - m2) * isd + m2;
      float nc = cur[jrow + e] + o;
      cur[jrow + e] = nc;
      yL[r][e] = nc;  // new cur row for next-head qkv
      if (flags & 1) out[jrow + e] = nc * (1.0f / NH);
    }
  }
  __syncthreads();

  // ---- qkv for next head from LDS new-cur rows; 8 waves split e-range ----
  if (flags & 2) {
    float aq[NQ] = {0, 0, 0, 0}, ak[NQ] = {0, 0, 0, 0}, av[NQ] = {0, 0, 0, 0};
    int e0 = wv * 64;
    for (int e = e0; e < e0 + 64; e++) {
      float wq = WTqn[e * DH + lane];
      float wk = WTkn[e * DH + lane];
      float wvv = WTvn[e * DH + lane];
#pragma unroll
      for (int r = 0; r < NQ; r++) {
        float xr = yL[r][e];
        aq[r] += xr * wq; ak[r] += xr * wk; av[r] += xr * wvv;
      }
    }
#pragma unroll
    for (int r = 0; r < NQ; r++) {
      qP[wv][0][r][lane] = aq[r];
      qP[wv][1][r][lane] = ak[r];
      qP[wv][2][r][lane] = av[r];
    }
    __syncthreads();
    for (int i = tid; i < 3 * NQ * DH; i += NT) {
      int o = i >> 8;
      int rem = i & 255;
      int r = rem >> 6, c = rem & 63;
      float s = 0;
#pragma unroll
      for (int w = 0; w < NW; w++) s += qP[w][o][r][c];
      float* dp = (o == 0 ? qn : (o == 1 ? kn : vn));
      dp[(size_t)(j0 + r) * DH + c] = s;
    }
  }
}

extern "C" void kernel_launch(void* const* d_in, const int* in_sizes, int n_in,
                              void* d_out, int out_size, void* d_ws, size_t ws_size,
                              hipStream_t stream) {
  const float* x   = (const float*)d_in[0];
  const float* Wq  = (const float*)d_in[1];
  const float* Wk  = (const float*)d_in[2];
  const float* Wvd = (const float*)d_in[3];
  const float* Wvu = (const float*)d_in[4];
  float* out = (float*)d_out;

  float* ws  = (float*)d_ws;
  float* cur = ws;                    // SQ*DE
  float* qA  = cur + SQ * DE;         // SQ*DH each
  float* kA  = qA + SQ * DH;
  float* vA  = kA + SQ * DH;
  float* qB  = vA + SQ * DH;
  float* kB  = qB + SQ * DH;
  float* vB  = kB + SQ * DH;
  float* WTq = vB + SQ * DH;          // NH*DE*DH each
  float* WTk = WTq + NH * DE * DH;
  float* WTv = WTk + NH * DE * DH;

  prep_kernel<<<4096, 256, 0, stream>>>(x, Wq, Wk, Wvd, cur, WTq, WTk, WTv);
  qkv0_kernel<<<SQ / NQ, NT, 0, stream>>>(x, WTq, WTk, WTv, qA, kA, vA);

  for (int h = 0; h < NH; h++) {
    const float* qi = (h & 1) ? qB : qA;
    const float* ki = (h & 1) ? kB : kA;
    const float* vi = (h & 1) ? vB : vA;
    float* qo = (h & 1) ? qA : qB;
    float* ko = (h & 1) ? kA : kB;
    float* vo = (h & 1) ? vA : vB;
    const size_t won = (size_t)(h + 1 < NH ? h + 1 : 0) * DE * DH;
    int flags = (h == NH - 1 ? 1 : 0) | (h < NH - 1 ? 2 : 0);
    fused_kernel<<<SQ / NQ, NT, 0, stream>>>(
        cur, qi, ki, vi, Wvu + (size_t)h * DE * DH,
        WTq + won, WTk + won, WTv + won, qo, ko, vo, out, flags);
  }
}

// Round 5
// 463.071 us; speedup vs baseline: 1.5285x; 1.5285x over previous
//
#include <hip/hip_runtime.h>
#include <math.h>

#define SQ 2048      // seq len
#define DE 512       // d_embedding
#define DH 64        // d_head
#define CW 128       // half-window
#define W2 256       // window width
#define NH 8         // heads
#define NQ 4         // queries per block
#define UW (W2 + NQ - 1)  // union window width = 259
#define NT 512       // threads per block
#define NW 8         // waves per block

// prep: WT[h][e][c] = W[h][c][e] for q/k/v ; VT[h][c][e] = Wvu[h][e][c]
__global__ __launch_bounds__(256) void prep_kernel(
    const float* __restrict__ Wq, const float* __restrict__ Wk,
    const float* __restrict__ Wvd, const float* __restrict__ Wvu,
    float* __restrict__ WTq, float* __restrict__ WTk, float* __restrict__ WTv,
    float* __restrict__ VT) {
  int i = blockIdx.x * 256 + threadIdx.x;
  if (i < NH * DE * DH) {
    int c = i & 63;
    int e = (i >> 6) & 511;
    int h = i >> 15;
    int src = (h * DH + c) * DE + e;
    WTq[i] = Wq[src];
    WTk[i] = Wk[src];
    WTv[i] = Wvd[src];
    VT[(h * DH + c) * DE + e] = Wvu[(h * DE + e) * DH + c];
  }
}

// qkv0: x -> cur copy + q/kT/v for head 0
__global__ __launch_bounds__(NT) void qkv0_kernel(
    const float* __restrict__ x,
    const float* __restrict__ WTq, const float* __restrict__ WTk,
    const float* __restrict__ WTv, float* __restrict__ cur,
    float* __restrict__ q, float* __restrict__ kT, float* __restrict__ v) {
  __shared__ float xL[NQ][DE];            // 8 KB
  __shared__ float qP[NW][3][NQ][DH];     // 24 KB
  int tid = threadIdx.x, lane = tid & 63, wv = tid >> 6;
  int j0 = blockIdx.x * NQ;

  float4 xv = ((const float4*)(x + (size_t)j0 * DE))[tid];
  ((float4*)xL)[tid] = xv;
  ((float4*)(cur + (size_t)j0 * DE))[tid] = xv;
  __syncthreads();

  float aq[NQ] = {0, 0, 0, 0}, ak[NQ] = {0, 0, 0, 0}, av[NQ] = {0, 0, 0, 0};
  int e0 = wv * 64;
#pragma unroll
  for (int i4 = 0; i4 < 16; i4++) {
    float4 xr[NQ];
#pragma unroll
    for (int r = 0; r < NQ; r++) xr[r] = ((const float4*)&xL[r][e0])[i4];
#pragma unroll
    for (int u = 0; u < 4; u++) {
      int e = e0 + i4 * 4 + u;
      float wq = WTq[e * DH + lane];
      float wk = WTk[e * DH + lane];
      float wvv = WTv[e * DH + lane];
#pragma unroll
      for (int r = 0; r < NQ; r++) {
        float xe = u == 0 ? xr[r].x : (u == 1 ? xr[r].y : (u == 2 ? xr[r].z : xr[r].w));
        aq[r] += xe * wq; ak[r] += xe * wk; av[r] += xe * wvv;
      }
    }
  }
#pragma unroll
  for (int r = 0; r < NQ; r++) {
    qP[wv][0][r][lane] = aq[r];
    qP[wv][1][r][lane] = ak[r];
    qP[wv][2][r][lane] = av[r];
  }
  __syncthreads();
  for (int i = tid; i < 3 * NQ * DH; i += NT) {
    int o = i >> 8;
    int rem = i & 255;
    int r = rem >> 6, c = rem & 63;
    float s = 0;
#pragma unroll
    for (int w = 0; w < NW; w++) s += qP[w][o][r][c];
    if (o == 0) q[(size_t)(j0 + r) * DH + c] = s;
    else if (o == 1) kT[(size_t)c * SQ + (j0 + r)] = s;
    else v[(size_t)(j0 + r) * DH + c] = s;
  }
}

// fused: attn(head h) [+ qkv(head h+1)]
// flags bit0: last head -> out = cur/8 ; bit1: compute next-head qkv
__global__ __launch_bounds__(NT) void fused_kernel(
    float* __restrict__ cur,
    const float* __restrict__ q, const float* __restrict__ kT,
    const float* __restrict__ v, const float* __restrict__ VT,
    const float* __restrict__ WTqn, const float* __restrict__ WTkn,
    const float* __restrict__ WTvn,
    float* __restrict__ qn, float* __restrict__ kTn, float* __restrict__ vn,
    float* __restrict__ out, int flags) {
  __shared__ float qL[NQ][DH];            // 1 KB
  __shared__ float sL[NQ][W2];            // 4 KB
  __shared__ float pL[NW][NQ][DH];        // 8 KB
  __shared__ float dL[NQ][DH];            // 1 KB
  __shared__ float yL[NQ][DE];            // 8 KB
  __shared__ float qP[NW][3][NQ][DH];     // 24 KB

  int tid = threadIdx.x, lane = tid & 63, wv = tid >> 6;
  int j0 = blockIdx.x * NQ;

  // ---- P0: stage q rows; preload all PV v-values (independent of anything) ----
  if (tid < NQ * DH) ((float*)qL)[tid] = q[(size_t)j0 * DH + tid];
  float vv[33];
  {
    int gbeg = 33 * wv;
#pragma unroll
    for (int i = 0; i < 33; i++) {
      int g = j0 - CW + gbeg + i;
      int gc = g < 0 ? 0 : (g >= SQ ? SQ - 1 : g);
      vv[i] = v[(size_t)gc * DH + lane];
    }
  }
  __syncthreads();

  // ---- P1: scores. wave wv covers goff = wv*64 + lane (waves 0-4 active) ----
  {
    int goff = wv * 64 + lane;
    if (goff < UW) {
      int g = j0 - CW + goff;
      bool valid = (g >= 0 && g < SQ);
      int gc = valid ? g : 0;
      float acc[NQ] = {0, 0, 0, 0};
#pragma unroll
      for (int d4 = 0; d4 < 16; d4++) {
        float4 qf[NQ];
#pragma unroll
        for (int r = 0; r < NQ; r++) qf[r] = ((const float4*)qL[r])[d4];
#pragma unroll
        for (int u = 0; u < 4; u++) {
          float kvv = kT[(size_t)(d4 * 4 + u) * SQ + gc];
#pragma unroll
          for (int r = 0; r < NQ; r++) {
            float qe = u == 0 ? qf[r].x : (u == 1 ? qf[r].y : (u == 2 ? qf[r].z : qf[r].w));
            acc[r] += qe * kvv;
          }
        }
      }
#pragma unroll
      for (int r = 0; r < NQ; r++) {
        int p = goff - r;
        if (p >= 0 && p < W2) sL[r][p] = valid ? acc[r] * 0.125f : -INFINITY;
      }
    }
  }
  __syncthreads();

  // ---- P2: softmax, wave per row ----
  if (wv < NQ) {
    int r = wv;
    float m = -INFINITY;
#pragma unroll
    for (int t = 0; t < 4; t++) m = fmaxf(m, sL[r][lane + 64 * t]);
#pragma unroll
    for (int off = 32; off; off >>= 1) m = fmaxf(m, __shfl_xor(m, off));
    float ex[4], ss = 0;
#pragma unroll
    for (int t = 0; t < 4; t++) {
      ex[t] = __expf(sL[r][lane + 64 * t] - m);
      ss += ex[t];
    }
#pragma unroll
    for (int off = 32; off; off >>= 1) ss += __shfl_xor(ss, off);
    float inv = 1.0f / ss;
#pragma unroll
    for (int t = 0; t < 4; t++) sL[r][lane + 64 * t] = ex[t] * inv;
  }
  __syncthreads();

  // ---- P3: PV from preloaded vv (no global loads) ----
  {
    float dacc[NQ] = {0, 0, 0, 0};
    int gbeg = 33 * wv;
#pragma unroll
    for (int i = 0; i < 33; i++) {
      int goff = gbeg + i;
      bool act = goff < UW;
#pragma unroll
      for (int r = 0; r < NQ; r++) {
        int p = goff - r;
        float w = (act && p >= 0 && p < W2) ? sL[r][p & 255] : 0.0f;
        dacc[r] += w * vv[i];
      }
    }
#pragma unroll
    for (int r = 0; r < NQ; r++) pL[wv][r][lane] = dacc[r];
  }
  __syncthreads();

  // ---- P4: reduce dL ----
  if (tid < NQ * DH) {
    int r = tid >> 6, c = tid & 63;
    float s = 0;
#pragma unroll
    for (int w = 0; w < NW; w++) s += pL[w][r][c];
    dL[r][c] = s;
  }
  __syncthreads();

  // ---- P5: upproj. wave wv owns e in [64wv, 64wv+64), lane = e-offset ----
  float c8[8];  // cur values for renorm (wave per row mapping), prefetched
  {
    int e0 = wv * 64;
    int e = e0 + lane;
    float cr[NQ];
#pragma unroll
    for (int r = 0; r < NQ; r++) cr[r] = cur[(size_t)(j0 + r) * DE + e];
    if (wv < NQ) {
      size_t jrow = (size_t)(j0 + wv) * DE;
#pragma unroll
      for (int t = 0; t < 8; t++) c8[t] = cur[jrow + lane + 64 * t];
    }
    float acc[NQ] = {0, 0, 0, 0};
#pragma unroll
    for (int c4 = 0; c4 < 16; c4++) {
      float4 df[NQ];
#pragma unroll
      for (int r = 0; r < NQ; r++) df[r] = ((const float4*)dL[r])[c4];
#pragma unroll
      for (int u = 0; u < 4; u++) {
        float w = VT[(size_t)(c4 * 4 + u) * DE + e];
#pragma unroll
        for (int r = 0; r < NQ; r++) {
          float de = u == 0 ? df[r].x : (u == 1 ? df[r].y : (u == 2 ? df[r].z : df[r].w));
          acc[r] += de * w;
        }
      }
    }
#pragma unroll
    for (int r = 0; r < NQ; r++) yL[r][e] = cr[r] + acc[r];
  }
  __syncthreads();

  // ---- P6: renorm + residual; wave per row ----
  if (wv < NQ) {
    int r = wv;
    size_t jrow = (size_t)(j0 + r) * DE;
    float s = 0;
#pragma unroll
    for (int t = 0; t < 8; t++) s += yL[r][lane + 64 * t];
#pragma unroll
    for (int off = 32; off; off >>= 1) s += __shfl_xor(s, off);
    float inv_m1 = 512.0f / s;
    float y2[8], s2 = 0, s2q = 0;
#pragma unroll
    for (int t = 0; t < 8; t++) {
      y2[t] = yL[r][lane + 64 * t] * inv_m1;
      s2 += y2[t];
      s2q += y2[t] * y2[t];
    }
#pragma unroll
    for (int off = 32; off; off >>= 1) {
      s2 += __shfl_xor(s2, off);
      s2q += __shfl_xor(s2q, off);
    }
    float m2 = s2 * (1.0f / 512.0f);
    float var = (s2q - 512.0f * m2 * m2) * (1.0f / 511.0f);
    float isd = 1.0f / sqrtf(var);
#pragma unroll
    for (int t = 0; t < 8; t++) {
      int e = lane + 64 * t;
      float o = (y2[t] - m2) * isd + m2;
      float nc = c8[t] + o;
      cur[jrow + e] = nc;
      yL[r][e] = nc;
      if (flags & 1) out[jrow + e] = nc * (1.0f / NH);
    }
  }
  __syncthreads();

  // ---- P7: next-head qkv from LDS new-cur; wave e-slice; full unroll ----
  if (flags & 2) {
    float aq[NQ] = {0, 0, 0, 0}, ak[NQ] = {0, 0, 0, 0}, av[NQ] = {0, 0, 0, 0};
    int e0 = wv * 64;
#pragma unroll
    for (int i4 = 0; i4 < 16; i4++) {
      float4 xr[NQ];
#pragma unroll
      for (int r = 0; r < NQ; r++) xr[r] = ((const float4*)&yL[r][e0])[i4];
#pragma unroll
      for (int u = 0; u < 4; u++) {
        int e = e0 + i4 * 4 + u;
        float wq = WTqn[e * DH + lane];
        float wk = WTkn[e * DH + lane];
        float wvv = WTvn[e * DH + lane];
#pragma unroll
        for (int r = 0; r < NQ; r++) {
          float xe = u == 0 ? xr[r].x : (u == 1 ? xr[r].y : (u == 2 ? xr[r].z : xr[r].w));
          aq[r] += xe * wq; ak[r] += xe * wk; av[r] += xe * wvv;
        }
      }
    }
#pragma unroll
    for (int r = 0; r < NQ; r++) {
      qP[wv][0][r][lane] = aq[r];
      qP[wv][1][r][lane] = ak[r];
      qP[wv][2][r][lane] = av[r];
    }
    __syncthreads();
    for (int i = tid; i < 3 * NQ * DH; i += NT) {
      int o = i >> 8;
      int rem = i & 255;
      int r = rem >> 6, c = rem & 63;
      float s = 0;
#pragma unroll
      for (int w = 0; w < NW; w++) s += qP[w][o][r][c];
      if (o == 0) qn[(size_t)(j0 + r) * DH + c] = s;
      else if (o == 1) kTn[(size_t)c * SQ + (j0 + r)] = s;
      else vn[(size_t)(j0 + r) * DH + c] = s;
    }
  }
}

extern "C" void kernel_launch(void* const* d_in, const int* in_sizes, int n_in,
                              void* d_out, int out_size, void* d_ws, size_t ws_size,
                              hipStream_t stream) {
  const float* x   = (const float*)d_in[0];
  const float* Wq  = (const float*)d_in[1];
  const float* Wk  = (const float*)d_in[2];
  const float* Wvd = (const float*)d_in[3];
  const float* Wvu = (const float*)d_in[4];
  float* out = (float*)d_out;

  float* ws  = (float*)d_ws;
  float* cur = ws;                    // SQ*DE
  float* qA  = cur + SQ * DE;         // SQ*DH each
  float* kA  = qA + SQ * DH;          // kT layout [DH][SQ]
  float* vA  = kA + SQ * DH;
  float* qB  = vA + SQ * DH;
  float* kB  = qB + SQ * DH;
  float* vB  = kB + SQ * DH;
  float* WTq = vB + SQ * DH;          // NH*DE*DH each
  float* WTk = WTq + NH * DE * DH;
  float* WTv = WTk + NH * DE * DH;
  float* VT  = WTv + NH * DE * DH;    // NH*DH*DE

  prep_kernel<<<NH * DE * DH / 256, 256, 0, stream>>>(Wq, Wk, Wvd, Wvu,
                                                      WTq, WTk, WTv, VT);
  qkv0_kernel<<<SQ / NQ, NT, 0, stream>>>(x, WTq, WTk, WTv, cur, qA, kA, vA);

  for (int h = 0; h < NH; h++) {
    const float* qi = (h & 1) ? qB : qA;
    const float* ki = (h & 1) ? kB : kA;
    const float* vi = (h & 1) ? vB : vA;
    float* qo = (h & 1) ? qA : qB;
    float* ko = (h & 1) ? kA : kB;
    float* vo = (h & 1) ? vA : vB;
    const size_t won = (size_t)(h + 1 < NH ? h + 1 : 0) * DE * DH;
    int flags = (h == NH - 1 ? 1 : 0) | (h < NH - 1 ? 2 : 0);
    fused_kernel<<<SQ / NQ, NT, 0, stream>>>(
        cur, qi, ki, vi, VT + (size_t)h * DH * DE,
        WTq + won, WTk + won, WTv + won, qo, ko, vo, out, flags);
  }
}

// Round 6
// 330.198 us; speedup vs baseline: 2.1436x; 1.4024x over previous
//
#include <hip/hip_runtime.h>
#include <math.h>

#define SQ 2048      // seq len
#define DE 512       // d_embedding
#define DH 64        // d_head
#define CW 128       // half-window
#define W2 256       // window width
#define NH 8         // heads
#define NQ 4         // queries per block
#define UW (W2 + NQ - 1)  // union window width = 259
#define NT 512       // threads per block
#define NW 8         // waves per block

// prep: WT[h][e][c] = W[h][c][e] for q/k/v ; VT[h][c][e] = Wvu[h][e][c]
__global__ __launch_bounds__(256) void prep_kernel(
    const float* __restrict__ Wq, const float* __restrict__ Wk,
    const float* __restrict__ Wvd, const float* __restrict__ Wvu,
    float* __restrict__ WTq, float* __restrict__ WTk, float* __restrict__ WTv,
    float* __restrict__ VT) {
  int i = blockIdx.x * 256 + threadIdx.x;
  if (i < NH * DE * DH) {
    int c = i & 63;
    int e = (i >> 6) & 511;
    int h = i >> 15;
    int src = (h * DH + c) * DE + e;
    WTq[i] = Wq[src];
    WTk[i] = Wk[src];
    WTv[i] = Wvd[src];
    VT[(h * DH + c) * DE + e] = Wvu[(h * DE + e) * DH + c];
  }
}

// qkv0: x -> cur copy + q/kT/v for head 0
__global__ __launch_bounds__(NT) void qkv0_kernel(
    const float* __restrict__ x,
    const float* __restrict__ WTq, const float* __restrict__ WTk,
    const float* __restrict__ WTv, float* __restrict__ cur,
    float* __restrict__ q, float* __restrict__ kT, float* __restrict__ v) {
  __shared__ float xL[NQ][DE];            // 8 KB
  __shared__ float qP[NW][3][NQ][DH];     // 24 KB
  int tid = threadIdx.x, lane = tid & 63, wv = tid >> 6;
  int j0 = blockIdx.x * NQ;

  float4 xv = ((const float4*)(x + (size_t)j0 * DE))[tid];
  ((float4*)xL)[tid] = xv;
  ((float4*)(cur + (size_t)j0 * DE))[tid] = xv;
  __syncthreads();

  float aq[NQ] = {0, 0, 0, 0}, ak[NQ] = {0, 0, 0, 0}, av[NQ] = {0, 0, 0, 0};
  int e0 = wv * 64;
#pragma unroll
  for (int i4 = 0; i4 < 16; i4++) {
    // chunk: 12 weight loads + 4 LDS float4 reads, then 48 FMA (short lifetimes)
    float wq[4], wk[4], wvv[4];
#pragma unroll
    for (int u = 0; u < 4; u++) {
      int e = e0 + i4 * 4 + u;
      wq[u] = WTq[e * DH + lane];
      wk[u] = WTk[e * DH + lane];
      wvv[u] = WTv[e * DH + lane];
    }
#pragma unroll
    for (int r = 0; r < NQ; r++) {
      float4 xr = ((const float4*)&xL[r][e0])[i4];
      aq[r] += xr.x * wq[0] + xr.y * wq[1] + xr.z * wq[2] + xr.w * wq[3];
      ak[r] += xr.x * wk[0] + xr.y * wk[1] + xr.z * wk[2] + xr.w * wk[3];
      av[r] += xr.x * wvv[0] + xr.y * wvv[1] + xr.z * wvv[2] + xr.w * wvv[3];
    }
  }
#pragma unroll
  for (int r = 0; r < NQ; r++) {
    qP[wv][0][r][lane] = aq[r];
    qP[wv][1][r][lane] = ak[r];
    qP[wv][2][r][lane] = av[r];
  }
  __syncthreads();
  for (int i = tid; i < 3 * NQ * DH; i += NT) {
    int o = i >> 8;
    int rem = i & 255;
    int r = rem >> 6, c = rem & 63;
    float s = 0;
#pragma unroll
    for (int w = 0; w < NW; w++) s += qP[w][o][r][c];
    if (o == 0) q[(size_t)(j0 + r) * DH + c] = s;
    else if (o == 1) kT[(size_t)c * SQ + (j0 + r)] = s;
    else v[(size_t)(j0 + r) * DH + c] = s;
  }
}

// fused: attn(head h) [+ qkv(head h+1)]
// flags bit0: last head -> out = cur/8 ; bit1: compute next-head qkv
__global__ __launch_bounds__(NT) void fused_kernel(
    float* __restrict__ cur,
    const float* __restrict__ q, const float* __restrict__ kT,
    const float* __restrict__ v, const float* __restrict__ VT,
    const float* __restrict__ WTqn, const float* __restrict__ WTkn,
    const float* __restrict__ WTvn,
    float* __restrict__ qn, float* __restrict__ kTn, float* __restrict__ vn,
    float* __restrict__ out, int flags) {
  __shared__ float qL[NQ][DH];            // 1 KB
  __shared__ float sL[NQ][W2];            // 4 KB
  __shared__ float pL[NW][NQ][DH];        // 8 KB
  __shared__ float dL[NQ][DH];            // 1 KB
  __shared__ float yL[NQ][DE];            // 8 KB
  __shared__ float qP[NW][3][NQ][DH];     // 24 KB

  int tid = threadIdx.x, lane = tid & 63, wv = tid >> 6;
  int j0 = blockIdx.x * NQ;

  // ---- P0: stage q rows ----
  if (tid < NQ * DH) ((float*)qL)[tid] = q[(size_t)j0 * DH + tid];
  __syncthreads();

  // ---- P1: scores. wave wv covers goff = wv*64 + lane (waves 0-4 active) ----
  {
    int goff = wv * 64 + lane;
    if (goff < UW) {
      int g = j0 - CW + goff;
      bool valid = (g >= 0 && g < SQ);
      int gc = valid ? g : 0;
      float acc[NQ] = {0, 0, 0, 0};
#pragma unroll
      for (int d4 = 0; d4 < 16; d4++) {
        float kc[4];
#pragma unroll
        for (int u = 0; u < 4; u++) kc[u] = kT[(size_t)(d4 * 4 + u) * SQ + gc];
#pragma unroll
        for (int r = 0; r < NQ; r++) {
          float4 qf = ((const float4*)qL[r])[d4];
          acc[r] += qf.x * kc[0] + qf.y * kc[1] + qf.z * kc[2] + qf.w * kc[3];
        }
      }
#pragma unroll
      for (int r = 0; r < NQ; r++) {
        int p = goff - r;
        if (p >= 0 && p < W2) sL[r][p] = valid ? acc[r] * 0.125f : -INFINITY;
      }
    }
  }
  __syncthreads();

  // ---- P2: softmax, wave per row ----
  if (wv < NQ) {
    int r = wv;
    float m = -INFINITY;
#pragma unroll
    for (int t = 0; t < 4; t++) m = fmaxf(m, sL[r][lane + 64 * t]);
#pragma unroll
    for (int off = 32; off; off >>= 1) m = fmaxf(m, __shfl_xor(m, off));
    float ex[4], ss = 0;
#pragma unroll
    for (int t = 0; t < 4; t++) {
      ex[t] = __expf(sL[r][lane + 64 * t] - m);
      ss += ex[t];
    }
#pragma unroll
    for (int off = 32; off; off >>= 1) ss += __shfl_xor(ss, off);
    float inv = 1.0f / ss;
#pragma unroll
    for (int t = 0; t < 4; t++) sL[r][lane + 64 * t] = ex[t] * inv;
  }
  __syncthreads();

  // ---- P3: PV, 3 chunks of 11 (register lifetime 11, not 33) ----
  {
    float dacc[NQ] = {0, 0, 0, 0};
    int gbeg = 33 * wv;
#pragma unroll
    for (int ch = 0; ch < 3; ch++) {
      float vc[11];
#pragma unroll
      for (int i = 0; i < 11; i++) {
        int goff = gbeg + ch * 11 + i;
        int g = j0 - CW + goff;
        int gc = g < 0 ? 0 : (g >= SQ ? SQ - 1 : g);
        vc[i] = v[(size_t)gc * DH + lane];
      }
#pragma unroll
      for (int i = 0; i < 11; i++) {
        int goff = gbeg + ch * 11 + i;
        bool act = goff < UW;
#pragma unroll
        for (int r = 0; r < NQ; r++) {
          int p = goff - r;
          float w = (act && p >= 0 && p < W2) ? sL[r][p & 255] : 0.0f;
          dacc[r] += w * vc[i];
        }
      }
    }
#pragma unroll
    for (int r = 0; r < NQ; r++) pL[wv][r][lane] = dacc[r];
  }
  __syncthreads();

  // ---- P4: reduce dL ----
  if (tid < NQ * DH) {
    int r = tid >> 6, c = tid & 63;
    float s = 0;
#pragma unroll
    for (int w = 0; w < NW; w++) s += pL[w][r][c];
    dL[r][c] = s;
  }
  __syncthreads();

  // ---- P5: upproj. wave wv owns e in [64wv, 64wv+64), lane = e-offset ----
  float c8[8];  // cur row for renorm (waves 0-3), prefetched early
  {
    int e0 = wv * 64;
    int e = e0 + lane;
    float cr[NQ];
#pragma unroll
    for (int r = 0; r < NQ; r++) cr[r] = cur[(size_t)(j0 + r) * DE + e];
    if (wv < NQ) {
      size_t jrow = (size_t)(j0 + wv) * DE;
#pragma unroll
      for (int t = 0; t < 8; t++) c8[t] = cur[jrow + lane + 64 * t];
    }
    float acc[NQ] = {0, 0, 0, 0};
#pragma unroll
    for (int c4 = 0; c4 < 16; c4++) {
      float wc[4];
#pragma unroll
      for (int u = 0; u < 4; u++) wc[u] = VT[(size_t)(c4 * 4 + u) * DE + e];
#pragma unroll
      for (int r = 0; r < NQ; r++) {
        float4 df = ((const float4*)dL[r])[c4];
        acc[r] += df.x * wc[0] + df.y * wc[1] + df.z * wc[2] + df.w * wc[3];
      }
    }
#pragma unroll
    for (int r = 0; r < NQ; r++) yL[r][e] = cr[r] + acc[r];
  }
  __syncthreads();

  // ---- P6: renorm + residual; wave per row ----
  if (wv < NQ) {
    int r = wv;
    size_t jrow = (size_t)(j0 + r) * DE;
    float s = 0;
#pragma unroll
    for (int t = 0; t < 8; t++) s += yL[r][lane + 64 * t];
#pragma unroll
    for (int off = 32; off; off >>= 1) s += __shfl_xor(s, off);
    float inv_m1 = 512.0f / s;
    float y2[8], s2 = 0, s2q = 0;
#pragma unroll
    for (int t = 0; t < 8; t++) {
      y2[t] = yL[r][lane + 64 * t] * inv_m1;
      s2 += y2[t];
      s2q += y2[t] * y2[t];
    }
#pragma unroll
    for (int off = 32; off; off >>= 1) {
      s2 += __shfl_xor(s2, off);
      s2q += __shfl_xor(s2q, off);
    }
    float m2 = s2 * (1.0f / 512.0f);
    float var = (s2q - 512.0f * m2 * m2) * (1.0f / 511.0f);
    float isd = 1.0f / sqrtf(var);
#pragma unroll
    for (int t = 0; t < 8; t++) {
      int e = lane + 64 * t;
      float o = (y2[t] - m2) * isd + m2;
      float nc = c8[t] + o;
      cur[jrow + e] = nc;
      yL[r][e] = nc;
      if (flags & 1) out[jrow + e] = nc * (1.0f / NH);
    }
  }
  __syncthreads();

  // ---- P7: next-head qkv from LDS new-cur; wave e-slice; chunked ----
  if (flags & 2) {
    float aq[NQ] = {0, 0, 0, 0}, ak[NQ] = {0, 0, 0, 0}, av[NQ] = {0, 0, 0, 0};
    int e0 = wv * 64;
#pragma unroll
    for (int i4 = 0; i4 < 16; i4++) {
      float wq[4], wk[4], wvv[4];
#pragma unroll
      for (int u = 0; u < 4; u++) {
        int e = e0 + i4 * 4 + u;
        wq[u] = WTqn[e * DH + lane];
        wk[u] = WTkn[e * DH + lane];
        wvv[u] = WTvn[e * DH + lane];
      }
#pragma unroll
      for (int r = 0; r < NQ; r++) {
        float4 xr = ((const float4*)&yL[r][e0])[i4];
        aq[r] += xr.x * wq[0] + xr.y * wq[1] + xr.z * wq[2] + xr.w * wq[3];
        ak[r] += xr.x * wk[0] + xr.y * wk[1] + xr.z * wk[2] + xr.w * wk[3];
        av[r] += xr.x * wvv[0] + xr.y * wvv[1] + xr.z * wvv[2] + xr.w * wvv[3];
      }
    }
#pragma unroll
    for (int r = 0; r < NQ; r++) {
      qP[wv][0][r][lane] = aq[r];
      qP[wv][1][r][lane] = ak[r];
      qP[wv][2][r][lane] = av[r];
    }
    __syncthreads();
    for (int i = tid; i < 3 * NQ * DH; i += NT) {
      int o = i >> 8;
      int rem = i & 255;
      int r = rem >> 6, c = rem & 63;
      float s = 0;
#pragma unroll
      for (int w = 0; w < NW; w++) s += qP[w][o][r][c];
      if (o == 0) qn[(size_t)(j0 + r) * DH + c] = s;
      else if (o == 1) kTn[(size_t)c * SQ + (j0 + r)] = s;
      else vn[(size_t)(j0 + r) * DH + c] = s;
    }
  }
}

extern "C" void kernel_launch(void* const* d_in, const int* in_sizes, int n_in,
                              void* d_out, int out_size, void* d_ws, size_t ws_size,
                              hipStream_t stream) {
  const float* x   = (const float*)d_in[0];
  const float* Wq  = (const float*)d_in[1];
  const float* Wk  = (const float*)d_in[2];
  const float* Wvd = (const float*)d_in[3];
  const float* Wvu = (const float*)d_in[4];
  float* out = (float*)d_out;

  float* ws  = (float*)d_ws;
  float* cur = ws;                    // SQ*DE
  float* qA  = cur + SQ * DE;         // SQ*DH each
  float* kA  = qA + SQ * DH;          // kT layout [DH][SQ]
  float* vA  = kA + SQ * DH;
  float* qB  = vA + SQ * DH;
  float* kB  = qB + SQ * DH;
  float* vB  = kB + SQ * DH;
  float* WTq = vB + SQ * DH;          // NH*DE*DH each
  float* WTk = WTq + NH * DE * DH;
  float* WTv = WTk + NH * DE * DH;
  float* VT  = WTv + NH * DE * DH;    // NH*DH*DE

  prep_kernel<<<NH * DE * DH / 256, 256, 0, stream>>>(Wq, Wk, Wvd, Wvu,
                                                      WTq, WTk, WTv, VT);
  qkv0_kernel<<<SQ / NQ, NT, 0, stream>>>(x, WTq, WTk, WTv, cur, qA, kA, vA);

  for (int h = 0; h < NH; h++) {
    const float* qi = (h & 1) ? qB : qA;
    const float* ki = (h & 1) ? kB : kA;
    const float* vi = (h & 1) ? vB : vA;
    float* qo = (h & 1) ? qA : qB;
    float* ko = (h & 1) ? kA : kB;
    float* vo = (h & 1) ? vA : vB;
    const size_t won = (size_t)(h + 1 < NH ? h + 1 : 0) * DE * DH;
    int flags = (h == NH - 1 ? 1 : 0) | (h < NH - 1 ? 2 : 0);
    fused_kernel<<<SQ / NQ, NT, 0, stream>>>(
        cur, qi, ki, vi, VT + (size_t)h * DH * DE,
        WTq + won, WTk + won, WTv + won, qo, ko, vo, out, flags);
  }
}